// Round 1
// baseline (324.179 us; speedup 1.0000x reference)
//
#include <hip/hip_runtime.h>

#define IRE (1.0f / 400.0f)

constexpr int W = 512;
constexpr int H = 512;
constexpr int NB = 64;
constexpr int ROWS = 32;
constexpr int CHUNKS = H / ROWS;   // 16
constexpr int STRIPS = 2;          // strip = 256 cols = 64 lanes * 4 floats

__device__ __forceinline__ void residuals3(
    float um, float vm, float ul, float vl, float ur, float vr,
    float ub, float vb, float ut, float vt,
    float& mass, float& momu, float& momv)
{
    float dudx = (ur - ul) * 0.5f;
    float dvdy = (vt - vb) * 0.5f;
    float ru = ur + um, lu = ul + um, tu_ = ut + um, bu = ub + um;
    float rv = vr + vm, lv = vl + vm, tv_ = vt + vm, bv = vb + vm;
    float du2dx = 0.25f * (ru * ru - lu * lu);
    float duvdy = 0.25f * (tu_ * tv_ - bu * bv);
    float dv2dy = 0.25f * (tv_ * tv_ - bv * bv);
    float dvudx = 0.25f * (rv * ru - lv * lu);
    float dudx2 = ur - 2.0f * um + ul;
    float dudy2 = ut - 2.0f * um + ub;
    float dvdx2 = vr - 2.0f * vm + vl;
    float dvdy2 = vt - 2.0f * vm + vb;
    mass = dudx + dvdy;
    momu = du2dx + duvdy - (dudx2 + dudy2) * IRE;
    momv = dvudx + dv2dy - (dvdx2 + dvdy2) * IRE;
}

__global__ __launch_bounds__(64) void loss_main(
    const float* __restrict__ pred, const float* __restrict__ trut,
    double* __restrict__ acc)
{
    const int lane = threadIdx.x;
    int bid = blockIdx.x;
    const int strip = bid % STRIPS; bid /= STRIPS;
    const int chunk = bid % CHUNKS; bid /= CHUNKS;
    const int b = bid;

    const int r0 = chunk * ROWS;
    const int js = strip * (64 * 4) + lane * 4;

    const size_t CH = (size_t)H * W;
    const float* g_tu = trut + (size_t)b * 2 * CH;
    const float* g_tv = g_tu + CH;
    const float* g_pu = pred + (size_t)b * 2 * CH;
    const float* g_pv = g_pu + CH;

    const int lo = (r0 > 0) ? r0 : 1;
    const int hi = (r0 + ROWS < H - 1) ? (r0 + ROWS) : (H - 1);

    float accMass = 0.0f, accMom = 0.0f, accL1 = 0.0f;

    float4 Ptu, Ptv, Ppu, Ppv;   // row i-1
    float4 Xtu, Xtv, Xpu, Xpv;   // row i
    float4 Ntu, Ntv, Npu, Npv;   // row i+1

    auto loadRow = [&](int r, float4& a, float4& bb, float4& c, float4& d) {
        const size_t off = (size_t)r * W + js;
        a  = *(const float4*)(g_tu + off);
        bb = *(const float4*)(g_tv + off);
        c  = *(const float4*)(g_pu + off);
        d  = *(const float4*)(g_pv + off);
        if (r >= r0 && r < r0 + ROWS) {  // each row counted exactly once for L1
            accL1 += fabsf(c.x - a.x) + fabsf(c.y - a.y) + fabsf(c.z - a.z) + fabsf(c.w - a.w)
                   + fabsf(d.x - bb.x) + fabsf(d.y - bb.y) + fabsf(d.z - bb.z) + fabsf(d.w - bb.w);
        }
    };

    loadRow(lo - 1, Ptu, Ptv, Ppu, Ppv);
    loadRow(lo,     Xtu, Xtv, Xpu, Xpv);
    loadRow(lo + 1, Ntu, Ntv, Npu, Npv);

    for (int i = lo; i < hi; ++i) {
        float4 Qtu = {0,0,0,0}, Qtv = {0,0,0,0}, Qpu = {0,0,0,0}, Qpv = {0,0,0,0};
        if (i + 2 <= hi) loadRow(i + 2, Qtu, Qtv, Qpu, Qpv);   // prefetch depth 1

        // j-1 / j+4 halo scalars from adjacent lanes (strip edges: direct load)
        float l_tu = __shfl_up(Xtu.w, 1);
        float l_tv = __shfl_up(Xtv.w, 1);
        float l_pu = __shfl_up(Xpu.w, 1);
        float l_pv = __shfl_up(Xpv.w, 1);
        float r_tu = __shfl_down(Xtu.x, 1);
        float r_tv = __shfl_down(Xtv.x, 1);
        float r_pu = __shfl_down(Xpu.x, 1);
        float r_pv = __shfl_down(Xpv.x, 1);
        if (lane == 0 && js > 0) {
            const size_t o = (size_t)i * W + js - 1;
            l_tu = g_tu[o]; l_tv = g_tv[o]; l_pu = g_pu[o]; l_pv = g_pv[o];
        }
        if (lane == 63 && js + 4 < W) {
            const size_t o = (size_t)i * W + js + 4;
            r_tu = g_tu[o]; r_tv = g_tv[o]; r_pu = g_pu[o]; r_pv = g_pv[o];
        }

        const float Ctu[6] = {l_tu, Xtu.x, Xtu.y, Xtu.z, Xtu.w, r_tu};
        const float Ctv[6] = {l_tv, Xtv.x, Xtv.y, Xtv.z, Xtv.w, r_tv};
        const float Cpu[6] = {l_pu, Xpu.x, Xpu.y, Xpu.z, Xpu.w, r_pu};
        const float Cpv[6] = {l_pv, Xpv.x, Xpv.y, Xpv.z, Xpv.w, r_pv};
        const float Pu[4] = {Ptu.x, Ptu.y, Ptu.z, Ptu.w};
        const float Pv[4] = {Ptv.x, Ptv.y, Ptv.z, Ptv.w};
        const float PU[4] = {Ppu.x, Ppu.y, Ppu.z, Ppu.w};
        const float PV[4] = {Ppv.x, Ppv.y, Ppv.z, Ppv.w};
        const float Nu[4] = {Ntu.x, Ntu.y, Ntu.z, Ntu.w};
        const float Nv[4] = {Ntv.x, Ntv.y, Ntv.z, Ntv.w};
        const float NU[4] = {Npu.x, Npu.y, Npu.z, Npu.w};
        const float NV[4] = {Npv.x, Npv.y, Npv.z, Npv.w};

        #pragma unroll
        for (int k = 0; k < 4; ++k) {
            const int j = js + k;
            if (j >= 1 && j <= W - 2) {
                float mT, uT, vT, mP, uP, vP;
                // reference: l/r = +-1 in dim2 (rows) -> prev/next; b/t = +-1 in dim3 (cols)
                residuals3(Ctu[k+1], Ctv[k+1], Pu[k], Pv[k], Nu[k], Nv[k],
                           Ctu[k],   Ctv[k],   Ctu[k+2], Ctv[k+2], mT, uT, vT);
                residuals3(Cpu[k+1], Cpv[k+1], PU[k], PV[k], NU[k], NV[k],
                           Cpu[k],   Cpv[k],   Cpu[k+2], Cpv[k+2], mP, uP, vP);
                accMass += fabsf(mT - mP);
                accMom  += fabsf(uT - uP) + fabsf(vT - vP);
            }
        }

        Ptu = Xtu; Ptv = Xtv; Ppu = Xpu; Ppv = Xpv;
        Xtu = Ntu; Xtv = Ntv; Xpu = Npu; Xpv = Npv;
        Ntu = Qtu; Ntv = Qtv; Npu = Qpu; Npv = Qpv;
    }

    float res = 5.0f * accMass + 25.0f * accMom;
    float l1  = accL1;
    #pragma unroll
    for (int off = 32; off > 0; off >>= 1) {
        res += __shfl_down(res, off);
        l1  += __shfl_down(l1, off);
    }
    if (lane == 0) {
        atomicAdd(&acc[0], (double)res);
        atomicAdd(&acc[1], (double)l1);
    }
}

__global__ void loss_final(const double* __restrict__ acc, float* __restrict__ out)
{
    const double nRes = 64.0 * 510.0 * 510.0;       // interior cells
    const double nL1  = 64.0 * 2.0 * 512.0 * 512.0; // all elements
    out[0] = (float)((acc[0] / nRes + acc[1] / nL1) / 3.0);
}

extern "C" void kernel_launch(void* const* d_in, const int* in_sizes, int n_in,
                              void* d_out, int out_size, void* d_ws, size_t ws_size,
                              hipStream_t stream)
{
    const float* pred = (const float*)d_in[0];
    const float* trut = (const float*)d_in[1];
    double* acc = (double*)d_ws;
    hipMemsetAsync(acc, 0, 2 * sizeof(double), stream);   // capture-safe async memset
    const int grid = NB * CHUNKS * STRIPS;                // 2048 blocks x 1 wave
    loss_main<<<grid, 64, 0, stream>>>(pred, trut, acc);
    loss_final<<<1, 1, 0, stream>>>(acc, (float*)d_out);
}

// Round 2
// 297.845 us; speedup vs baseline: 1.0884x; 1.0884x over previous
//
#include <hip/hip_runtime.h>

#define IRE (1.0f / 400.0f)

constexpr int W = 512;
constexpr int H = 512;
constexpr int NB = 64;
constexpr int ROWS = 8;            // small chunk -> 8192 blocks -> 32 waves/CU
constexpr int CHUNKS = H / ROWS;   // 64
constexpr int STRIPS = 2;          // strip = 256 cols = 64 lanes * 4 floats
constexpr int GRID = NB * CHUNKS * STRIPS;  // 8192

__device__ __forceinline__ void residuals3(
    float um, float vm, float ul, float vl, float ur, float vr,
    float ub, float vb, float ut, float vt,
    float& mass, float& momu, float& momv)
{
    float dudx = (ur - ul) * 0.5f;
    float dvdy = (vt - vb) * 0.5f;
    float ru = ur + um, lu = ul + um, tu_ = ut + um, bu = ub + um;
    float rv = vr + vm, lv = vl + vm, tv_ = vt + vm, bv = vb + vm;
    float du2dx = 0.25f * (ru * ru - lu * lu);
    float duvdy = 0.25f * (tu_ * tv_ - bu * bv);
    float dv2dy = 0.25f * (tv_ * tv_ - bv * bv);
    float dvudx = 0.25f * (rv * ru - lv * lu);
    float dudx2 = ur - 2.0f * um + ul;
    float dudy2 = ut - 2.0f * um + ub;
    float dvdx2 = vr - 2.0f * vm + vl;
    float dvdy2 = vt - 2.0f * vm + vb;
    mass = dudx + dvdy;
    momu = du2dx + duvdy - (dudx2 + dudy2) * IRE;
    momv = dvudx + dv2dy - (dvdx2 + dvdy2) * IRE;
}

__global__ __launch_bounds__(64) void loss_main(
    const float* __restrict__ pred, const float* __restrict__ trut,
    double* __restrict__ partial)
{
    const int lane = threadIdx.x;
    int bid = blockIdx.x;
    const int strip = bid % STRIPS; bid /= STRIPS;
    const int chunk = bid % CHUNKS; bid /= CHUNKS;
    const int b = bid;

    const int r0 = chunk * ROWS;
    const int js = strip * (64 * 4) + lane * 4;

    const size_t CH = (size_t)H * W;
    const float* g_tu = trut + (size_t)b * 2 * CH;
    const float* g_tv = g_tu + CH;
    const float* g_pu = pred + (size_t)b * 2 * CH;
    const float* g_pv = g_pu + CH;

    const int lo = (r0 > 0) ? r0 : 1;
    const int hi = (r0 + ROWS < H - 1) ? (r0 + ROWS) : (H - 1);

    float accMass = 0.0f, accMom = 0.0f, accL1 = 0.0f;

    float4 Ptu, Ptv, Ppu, Ppv;   // row i-1
    float4 Xtu, Xtv, Xpu, Xpv;   // row i
    float4 Ntu, Ntv, Npu, Npv;   // row i+1

    auto loadRow = [&](int r, float4& a, float4& bb, float4& c, float4& d) {
        const size_t off = (size_t)r * W + js;
        a  = *(const float4*)(g_tu + off);
        bb = *(const float4*)(g_tv + off);
        c  = *(const float4*)(g_pu + off);
        d  = *(const float4*)(g_pv + off);
        if (r >= r0 && r < r0 + ROWS) {  // each row counted exactly once for L1
            accL1 += fabsf(c.x - a.x) + fabsf(c.y - a.y) + fabsf(c.z - a.z) + fabsf(c.w - a.w)
                   + fabsf(d.x - bb.x) + fabsf(d.y - bb.y) + fabsf(d.z - bb.z) + fabsf(d.w - bb.w);
        }
    };

    loadRow(lo - 1, Ptu, Ptv, Ppu, Ppv);
    loadRow(lo,     Xtu, Xtv, Xpu, Xpv);
    loadRow(lo + 1, Ntu, Ntv, Npu, Npv);

    for (int i = lo; i < hi; ++i) {
        float4 Qtu = {0,0,0,0}, Qtv = {0,0,0,0}, Qpu = {0,0,0,0}, Qpv = {0,0,0,0};
        if (i + 2 <= hi) loadRow(i + 2, Qtu, Qtv, Qpu, Qpv);   // prefetch depth 1

        // j-1 / j+4 halo scalars from adjacent lanes (strip edges: direct load)
        float l_tu = __shfl_up(Xtu.w, 1);
        float l_tv = __shfl_up(Xtv.w, 1);
        float l_pu = __shfl_up(Xpu.w, 1);
        float l_pv = __shfl_up(Xpv.w, 1);
        float r_tu = __shfl_down(Xtu.x, 1);
        float r_tv = __shfl_down(Xtv.x, 1);
        float r_pu = __shfl_down(Xpu.x, 1);
        float r_pv = __shfl_down(Xpv.x, 1);
        if (lane == 0 && js > 0) {
            const size_t o = (size_t)i * W + js - 1;
            l_tu = g_tu[o]; l_tv = g_tv[o]; l_pu = g_pu[o]; l_pv = g_pv[o];
        }
        if (lane == 63 && js + 4 < W) {
            const size_t o = (size_t)i * W + js + 4;
            r_tu = g_tu[o]; r_tv = g_tv[o]; r_pu = g_pu[o]; r_pv = g_pv[o];
        }

        const float Ctu[6] = {l_tu, Xtu.x, Xtu.y, Xtu.z, Xtu.w, r_tu};
        const float Ctv[6] = {l_tv, Xtv.x, Xtv.y, Xtv.z, Xtv.w, r_tv};
        const float Cpu[6] = {l_pu, Xpu.x, Xpu.y, Xpu.z, Xpu.w, r_pu};
        const float Cpv[6] = {l_pv, Xpv.x, Xpv.y, Xpv.z, Xpv.w, r_pv};
        const float Pu[4] = {Ptu.x, Ptu.y, Ptu.z, Ptu.w};
        const float Pv[4] = {Ptv.x, Ptv.y, Ptv.z, Ptv.w};
        const float PU[4] = {Ppu.x, Ppu.y, Ppu.z, Ppu.w};
        const float PV[4] = {Ppv.x, Ppv.y, Ppv.z, Ppv.w};
        const float Nu[4] = {Ntu.x, Ntu.y, Ntu.z, Ntu.w};
        const float Nv[4] = {Ntv.x, Ntv.y, Ntv.z, Ntv.w};
        const float NU[4] = {Npu.x, Npu.y, Npu.z, Npu.w};
        const float NV[4] = {Npv.x, Npv.y, Npv.z, Npv.w};

        #pragma unroll
        for (int k = 0; k < 4; ++k) {
            const int j = js + k;
            if (j >= 1 && j <= W - 2) {
                float mT, uT, vT, mP, uP, vP;
                residuals3(Ctu[k+1], Ctv[k+1], Pu[k], Pv[k], Nu[k], Nv[k],
                           Ctu[k],   Ctv[k],   Ctu[k+2], Ctv[k+2], mT, uT, vT);
                residuals3(Cpu[k+1], Cpv[k+1], PU[k], PV[k], NU[k], NV[k],
                           Cpu[k],   Cpv[k],   Cpu[k+2], Cpv[k+2], mP, uP, vP);
                accMass += fabsf(mT - mP);
                accMom  += fabsf(uT - uP) + fabsf(vT - vP);
            }
        }

        Ptu = Xtu; Ptv = Xtv; Ppu = Xpu; Ppv = Xpv;
        Xtu = Ntu; Xtv = Ntv; Xpu = Npu; Xpv = Npv;
        Ntu = Qtu; Ntv = Qtv; Npu = Qpu; Npv = Qpv;
    }

    float res = 5.0f * accMass + 25.0f * accMom;
    float l1  = accL1;
    #pragma unroll
    for (int off = 32; off > 0; off >>= 1) {
        res += __shfl_down(res, off);
        l1  += __shfl_down(l1, off);
    }
    if (lane == 0) {   // per-block partials: no memset, no atomic contention
        partial[(size_t)blockIdx.x * 2 + 0] = (double)res;
        partial[(size_t)blockIdx.x * 2 + 1] = (double)l1;
    }
}

__global__ __launch_bounds__(256) void loss_final(
    const double* __restrict__ partial, float* __restrict__ out)
{
    __shared__ double sres[4], sl1[4];
    const int t = threadIdx.x;
    double res = 0.0, l1 = 0.0;
    for (int i = t; i < GRID; i += 256) {
        res += partial[(size_t)i * 2 + 0];
        l1  += partial[(size_t)i * 2 + 1];
    }
    #pragma unroll
    for (int off = 32; off > 0; off >>= 1) {
        res += __shfl_down(res, off);
        l1  += __shfl_down(l1, off);
    }
    const int wave = t >> 6;
    if ((t & 63) == 0) { sres[wave] = res; sl1[wave] = l1; }
    __syncthreads();
    if (t == 0) {
        res = sres[0] + sres[1] + sres[2] + sres[3];
        l1  = sl1[0] + sl1[1] + sl1[2] + sl1[3];
        const double nRes = 64.0 * 510.0 * 510.0;
        const double nL1  = 64.0 * 2.0 * 512.0 * 512.0;
        out[0] = (float)((res / nRes + l1 / nL1) / 3.0);
    }
}

extern "C" void kernel_launch(void* const* d_in, const int* in_sizes, int n_in,
                              void* d_out, int out_size, void* d_ws, size_t ws_size,
                              hipStream_t stream)
{
    const float* pred = (const float*)d_in[0];
    const float* trut = (const float*)d_in[1];
    double* partial = (double*)d_ws;   // 8192*2 doubles = 128 KB, written before read
    loss_main<<<GRID, 64, 0, stream>>>(pred, trut, partial);
    loss_final<<<1, 256, 0, stream>>>(partial, (float*)d_out);
}